// Round 19
// baseline (161.322 us; speedup 1.0000x reference)
//
#include <hip/hip_runtime.h>
#include <hip/hip_bf16.h>
#include <math.h>

#define H 128
#define W 128
#define HW (H*W)
#define BATCH 2

typedef __attribute__((ext_vector_type(8))) short          bf16x8;
typedef __attribute__((ext_vector_type(4))) float          f32x4;
typedef __attribute__((ext_vector_type(8))) unsigned short u16x8;

__device__ __forceinline__ float sigmoidf_(float x){ return 1.0f/(1.0f + expf(-x)); }

__device__ __forceinline__ unsigned short f2bf(float f) {
    __hip_bfloat16 h = __float2bfloat16(f);          // RTNE
    return __builtin_bit_cast(unsigned short, h);
}
__device__ __forceinline__ float bf2f(unsigned short b) {
    return __uint_as_float(((unsigned)b) << 16);
}
__device__ __forceinline__ float bflo(unsigned u){ return __uint_as_float(u << 16); }
__device__ __forceinline__ float bfhi(unsigned u){ return __uint_as_float(u & 0xFFFF0000u); }

// ---------------------------------------------------------------------------
// prep_all: blocks 0/1 zero the per-XCD GN-stat accumulators (8 copies x 64);
// blocks 0..511 transpose x [B][64][HW] f32 -> xt [B][HW][64] bf16;
// blocks 512+ weight layouts (tap-major bf16).
// ---------------------------------------------------------------------------
__global__ __launch_bounds__(256) void prep_all(
    const float* __restrict__ x,
    const float* __restrict__ wc1, const float* __restrict__ wc2,
    const float* __restrict__ wp1, const float* __restrict__ wm1,
    const float* __restrict__ wp2, const float* __restrict__ wm2,
    unsigned short* __restrict__ xt,
    unsigned short* __restrict__ wtp1, unsigned short* __restrict__ wtp2,
    unsigned short* __restrict__ wop1, unsigned short* __restrict__ wop2,
    float* __restrict__ stats1, float* __restrict__ stats2)
{
    __shared__ float tile[64][65];
    if (blockIdx.x < 512) {
        if (blockIdx.x == 0) {
            stats1[threadIdx.x] = 0.f; stats1[threadIdx.x + 256] = 0.f;
        } else if (blockIdx.x == 1) {
            stats2[threadIdx.x] = 0.f; stats2[threadIdx.x + 256] = 0.f;
        }
        int blk = blockIdx.x;
        int b  = blk >> 8;
        int p0 = (blk & 255) * 64;
        int tr = threadIdx.x >> 6;
        int tc = threadIdx.x & 63;
        #pragma unroll
        for (int r = 0; r < 16; r++) {
            int c = r * 4 + tr;
            tile[c][tc] = x[((size_t)b * 64 + c) * HW + p0 + tc];
        }
        __syncthreads();
        #pragma unroll
        for (int r = 0; r < 16; r++) {
            int p = r * 4 + tr;
            xt[((size_t)b * HW + p0 + p) * 64 + tc] = f2bf(tile[tc][p]);
        }
        return;
    }
    const int s1 = 64 * 9 * 64, s2 = 64 * 9 * 128;
    const int s3 = 32 * 9 * 64, s4 = 32 * 9 * 128;
    int t = (blockIdx.x - 512) * 256 + threadIdx.x;
    if (t < s1) {
        int oc = t / (9 * 64); int r = t - oc * (9 * 64);
        int n = r / 64, c = r - n * 64;
        wtp1[t] = f2bf(wc1[((size_t)oc * 64 + c) * 9 + n]);
        return;
    }
    t -= s1;
    if (t < s2) {
        int oc = t / (9 * 128); int r = t - oc * (9 * 128);
        int n = r / 128, c = r - n * 128;
        wtp2[t] = f2bf(wc2[((size_t)oc * 128 + c) * 9 + n]);
        return;
    }
    t -= s2;
    if (t < s3) {
        int oc = t / (9 * 64); int r = t - oc * (9 * 64);
        int n = r / 64, c = r - n * 64;
        float v = 0.f;
        if (oc < 18)      v = wp1[((size_t)oc * 64 + c) * 9 + n];
        else if (oc < 27) v = wm1[((size_t)(oc - 18) * 64 + c) * 9 + n];
        wop1[t] = f2bf(v);
        return;
    }
    t -= s3;
    if (t < s4) {
        int oc = t / (9 * 128); int r = t - oc * (9 * 128);
        int n = r / 128, c = r - n * 128;
        float v = 0.f;
        if (oc < 18)      v = wp2[((size_t)oc * 128 + c) * 9 + n];
        else if (oc < 27) v = wm2[((size_t)(oc - 18) * 128 + c) * 9 + n];
        wop2[t] = f2bf(v);
    }
}

// ---------------------------------------------------------------------------
// Fused DSA stage, WAVE-INDEPENDENT: 4 waves per block, each wave owns
// 16 pixels end-to-end. Per-wave LDS slices; LDS write->read ordered by
// lgkmcnt within the wave -> ZERO __syncthreads in the whole kernel.
// Sampling keeps the coalesced (pixel, segment) map. Weights read from
// L2 directly (147 KB, cache-hot). GN stats: per-wave reduce -> per-XCD
// atomics. Chunk = one tap (full CIN), 9 chunks.
// ---------------------------------------------------------------------------
template<int CIN>
__global__ __launch_bounds__(256, 4) void dsa_fused(
    const unsigned short* __restrict__ xt,  // [B][HW][CIN] bf16
    const unsigned short* __restrict__ wop, // [32][9*CIN] bf16 tap-major
    const unsigned short* __restrict__ wtp, // [64][9*CIN] bf16 tap-major
    const float* __restrict__ bp,           // [18]
    const float* __restrict__ bm,           // [9]
    float* __restrict__ out,                // [B][64][HW]
    float* __restrict__ stats)              // [8][64] per-XCD sums
{
    constexpr int SEG  = CIN / 8;            // 8 or 16 segs per pixel
    constexpr int TPL  = CIN / 32;           // sampling tasks per lane: 2 or 4
    constexpr int SH   = (SEG == 16) ? 4 : 3;
    constexpr int SROW = CIN + 4;
    constexpr int KS   = CIN / 32;           // MFMA k-steps per tap
    __shared__ __align__(16) unsigned short sbuf[4][16][SROW];
    __shared__ __align__(16) unsigned short meta[4][9][16][8];
    __shared__ float offlds[4][27][20];

    int tid  = threadIdx.x;
    int bid  = blockIdx.x;                  // 512 blocks, XCD-bijective swizzle
    int wgid = (bid & 7) * 64 + (bid >> 3);
    int pix0 = wgid * 64;
    int b    = pix0 >> 14;
    int base = pix0 & (HW - 1);
    int i    = base >> 7;
    int j0   = base & 127;

    int lane = tid & 63, wv = tid >> 6;     // 4 independent waves
    int lr = lane & 15, lg = lane >> 4;
    int jw = j0 + wv * 16;                  // wave's column start

    const unsigned short* xtb = xt + (size_t)b * HW * CIN;
    const u16x8 zero8 = {0,0,0,0,0,0,0,0};

    // ================= phase 1: offset/mask conv (per wave) ===============
    {
        f32x4 oa0 = {0.f,0.f,0.f,0.f}, oa1 = {0.f,0.f,0.f,0.f};
        const unsigned short* wb0 = wop + (size_t)lr * (9 * CIN) + lg * 8;
        const unsigned short* wb1 = wb0 + (size_t)16 * (9 * CIN);
        for (int n = 0; n < 9; n++) {
            int di = n / 3 - 1, dj = n - (n / 3) * 3 - 1;
            int ii = i + di;
            bool rowok = (ii >= 0 && ii < H);
            #pragma unroll
            for (int t2 = 0; t2 < TPL; t2++) {
                int T = t2 * 64 + lane;
                int sp = T >> SH, scl = T & (SEG - 1);
                int jj = jw + sp + dj;
                bool ok = rowok && (jj >= 0 && jj < W);
                u16x8 v = ok ? *reinterpret_cast<const u16x8*>(
                                   xtb + (size_t)(ii * W + jj) * CIN + scl * 8)
                             : zero8;
                *reinterpret_cast<u16x8*>(&sbuf[wv][sp][scl * 8]) = v;
            }
            #pragma unroll
            for (int ks = 0; ks < KS; ks++) {
                bf16x8 bfr = *reinterpret_cast<const bf16x8*>(&sbuf[wv][lr][ks * 32 + lg * 8]);
                bf16x8 a0  = *reinterpret_cast<const bf16x8*>(wb0 + n * CIN + ks * 32);
                bf16x8 a1  = *reinterpret_cast<const bf16x8*>(wb1 + n * CIN + ks * 32);
                oa0 = __builtin_amdgcn_mfma_f32_16x16x32_bf16(a0, bfr, oa0, 0, 0, 0);
                oa1 = __builtin_amdgcn_mfma_f32_16x16x32_bf16(a1, bfr, oa1, 0, 0, 0);
            }
        }
        // D: col = lr (pixel), row = lg*4 + r within each 16-oc band
        #pragma unroll
        for (int r = 0; r < 4; r++) {
            int oc0 = lg * 4 + r;                 // 0..15: offsets
            offlds[wv][oc0][lr] = oa0[r] + bp[oc0];
            int oc1 = 16 + lg * 4 + r;            // 16..31
            if (oc1 < 27) {
                float v = oa1[r];
                v = (oc1 < 18) ? (v + bp[oc1]) : sigmoidf_(v + bm[oc1 - 18]);
                offlds[wv][oc1][lr] = v;
            }
        }
    }

    // ================= phase 2: bilinear meta (144 tasks per wave) ========
    for (int task = lane; task < 144; task += 64) {
        int p = task & 15, n = task >> 4;
        int j = jw + p;
        float px = offlds[wv][n][p]     + (float)(n / 3 - 1) + (float)(i + 1);
        float py = offlds[wv][9 + n][p] + (float)(n % 3 - 1) + (float)(j + 1);
        float mk = offlds[wv][18 + n][p];
        float fx = floorf(px), fy = floorf(py);
        const float lim = 129.0f;
        int qltx = (int)fminf(fmaxf(fx, 0.f), lim);
        int qlty = (int)fminf(fmaxf(fy, 0.f), lim);
        int qrbx = (int)fminf(fmaxf(fx + 1.f, 0.f), lim);
        int qrby = (int)fminf(fmaxf(fy + 1.f, 0.f), lim);
        float pxc = fminf(fmaxf(px, 0.f), lim);
        float pyc = fminf(fmaxf(py, 0.f), lim);
        float gxl = 1.f + ((float)qltx - pxc);
        float gxr = 1.f - ((float)qrbx - pxc);
        float gyl = 1.f + ((float)qlty - pyc);
        float gyr = 1.f - ((float)qrby - pyc);
        int   xs[4] = {qltx, qrbx, qltx, qrbx};
        int   ys[4] = {qlty, qrby, qrby, qlty};
        float gs[4] = {gxl * gyl, gxr * gyr, gxl * gyr, gxr * gyl};
        u16x8 m;
        #pragma unroll
        for (int q = 0; q < 4; q++) {
            int qx = xs[q], qy = ys[q];
            bool valid = (qx >= 1 && qx <= H && qy >= 1 && qy <= W);
            m[q]     = valid ? (unsigned short)((qx - 1) * W + (qy - 1)) : (unsigned short)0;
            m[4 + q] = f2bf(valid ? gs[q] * mk : 0.f);
        }
        *reinterpret_cast<u16x8*>(&meta[wv][n][p][0]) = m;
    }

    // ================= phase 3: deformable conv (per wave) ================
    {
        f32x4 ac0 = {0.f,0.f,0.f,0.f}, ac1 = {0.f,0.f,0.f,0.f};
        f32x4 ac2 = {0.f,0.f,0.f,0.f}, ac3 = {0.f,0.f,0.f,0.f};
        const unsigned short* wt0 = wtp + (size_t)lr * (9 * CIN) + lg * 8;
        const unsigned short* wt1 = wt0 + (size_t)16 * (9 * CIN);
        const unsigned short* wt2 = wt0 + (size_t)32 * (9 * CIN);
        const unsigned short* wt3 = wt0 + (size_t)48 * (9 * CIN);

        for (int n = 0; n < 9; n++) {
            #pragma unroll
            for (int t2 = 0; t2 < TPL; t2++) {
                int T = t2 * 64 + lane;
                int sp = T >> SH, scl = T & (SEG - 1);
                u16x8 gm = *reinterpret_cast<const u16x8*>(&meta[wv][n][sp][0]);
                const unsigned short* cb = xtb + scl * 8;
                u16x8 v0 = *reinterpret_cast<const u16x8*>(cb + (size_t)gm[0] * CIN);
                u16x8 v1 = *reinterpret_cast<const u16x8*>(cb + (size_t)gm[1] * CIN);
                u16x8 v2 = *reinterpret_cast<const u16x8*>(cb + (size_t)gm[2] * CIN);
                u16x8 v3 = *reinterpret_cast<const u16x8*>(cb + (size_t)gm[3] * CIN);
                float w0 = bf2f(gm[4]), w1 = bf2f(gm[5]);
                float w2 = bf2f(gm[6]), w3 = bf2f(gm[7]);
                const unsigned* d0 = reinterpret_cast<const unsigned*>(&v0);
                const unsigned* d1 = reinterpret_cast<const unsigned*>(&v1);
                const unsigned* d2 = reinterpret_cast<const unsigned*>(&v2);
                const unsigned* d3 = reinterpret_cast<const unsigned*>(&v3);
                u16x8 o;
                #pragma unroll
                for (int d = 0; d < 4; d++) {
                    float lo = bflo(d0[d]) * w0, hi = bfhi(d0[d]) * w0;
                    lo = fmaf(bflo(d1[d]), w1, lo); hi = fmaf(bfhi(d1[d]), w1, hi);
                    lo = fmaf(bflo(d2[d]), w2, lo); hi = fmaf(bfhi(d2[d]), w2, hi);
                    lo = fmaf(bflo(d3[d]), w3, lo); hi = fmaf(bfhi(d3[d]), w3, hi);
                    o[2 * d]     = f2bf(lo);
                    o[2 * d + 1] = f2bf(hi);
                }
                *reinterpret_cast<u16x8*>(&sbuf[wv][sp][scl * 8]) = o;
            }
            #pragma unroll
            for (int ks = 0; ks < KS; ks++) {
                bf16x8 bfr = *reinterpret_cast<const bf16x8*>(&sbuf[wv][lr][ks * 32 + lg * 8]);
                int wo = n * CIN + ks * 32;
                bf16x8 a0 = *reinterpret_cast<const bf16x8*>(wt0 + wo);
                bf16x8 a1 = *reinterpret_cast<const bf16x8*>(wt1 + wo);
                bf16x8 a2 = *reinterpret_cast<const bf16x8*>(wt2 + wo);
                bf16x8 a3 = *reinterpret_cast<const bf16x8*>(wt3 + wo);
                ac0 = __builtin_amdgcn_mfma_f32_16x16x32_bf16(a0, bfr, ac0, 0, 0, 0);
                ac1 = __builtin_amdgcn_mfma_f32_16x16x32_bf16(a1, bfr, ac1, 0, 0, 0);
                ac2 = __builtin_amdgcn_mfma_f32_16x16x32_bf16(a2, bfr, ac2, 0, 0, 0);
                ac3 = __builtin_amdgcn_mfma_f32_16x16x32_bf16(a3, bfr, ac3, 0, 0, 0);
            }
        }

        // stores: oc = band*16 + lg*4 + r, pixel = base + wv*16 + lr
        int pixo = base + wv * 16 + lr;
        float* o0 = out + ((size_t)b * 64 + lg * 4) * HW + pixo;
        float* o1 = o0 + (size_t)16 * HW;
        float* o2 = o0 + (size_t)32 * HW;
        float* o3 = o0 + (size_t)48 * HW;
        #pragma unroll
        for (int r = 0; r < 4; r++) {
            o0[(size_t)r * HW] = ac0[r];
            o1[(size_t)r * HW] = ac1[r];
            o2[(size_t)r * HW] = ac2[r];
            o3[(size_t)r * HW] = ac3[r];
        }

        // ---- GN stats: per-wave reduce over lr, per-XCD atomics ----
        float s0 = 0.f, t0 = 0.f, s1 = 0.f, t1 = 0.f;
        float s2 = 0.f, t2 = 0.f, s3 = 0.f, t3 = 0.f;
        #pragma unroll
        for (int r = 0; r < 4; r++) {
            s0 += ac0[r]; t0 += ac0[r] * ac0[r];
            s1 += ac1[r]; t1 += ac1[r] * ac1[r];
            s2 += ac2[r]; t2 += ac2[r] * ac2[r];
            s3 += ac3[r]; t3 += ac3[r] * ac3[r];
        }
        #pragma unroll
        for (int d = 1; d < 16; d <<= 1) {
            s0 += __shfl_xor(s0, d); t0 += __shfl_xor(t0, d);
            s1 += __shfl_xor(s1, d); t1 += __shfl_xor(t1, d);
            s2 += __shfl_xor(s2, d); t2 += __shfl_xor(t2, d);
            s3 += __shfl_xor(s3, d); t3 += __shfl_xor(t3, d);
        }
        if (lr == 0) {
            float* sb = stats + (bid & 7) * 64 + b * 16;   // per-XCD copy
            atomicAdd(&sb[lg],           s0);  atomicAdd(&sb[32 + lg],      t0);
            atomicAdd(&sb[4 + lg],       s1);  atomicAdd(&sb[32 + 4 + lg],  t1);
            atomicAdd(&sb[8 + lg],       s2);  atomicAdd(&sb[32 + 8 + lg],  t2);
            atomicAdd(&sb[12 + lg],      s3);  atomicAdd(&sb[32 + 12 + lg], t3);
        }
    }
}

// ---------------------------------------------------------------------------
// Fused: GN finalize (sum 8 per-XCD copies) + halo channel-mean/max +
// 3x3 sigmoid conv + GN+relu + scale + concat + transpose -> bf16 catt
// ---------------------------------------------------------------------------
__global__ __launch_bounds__(256) void attn_cat_t(
    const float* __restrict__ dc, const float* __restrict__ stats,
    const float* __restrict__ gamma, const float* __restrict__ beta,
    const float* __restrict__ wa, const float* __restrict__ ba,
    const float* __restrict__ wb, const float* __restrict__ bb,
    unsigned short* __restrict__ catt)
{
    __shared__ float tile[64][65];
    __shared__ float cm_l[3][66], cx_l[3][66];
    __shared__ float avs[64], mvs[64];
    __shared__ float mg[16], rg[16], gam[64], bet[64];
    int blk = blockIdx.x;               // 512
    int b  = blk >> 8;
    int p0 = (blk & 255) * 64;
    int i  = p0 >> 7;
    int j0 = p0 & 127;
    int tx = threadIdx.x;

    if (tx < 16) {
        float s = 0.f, q = 0.f;
        #pragma unroll
        for (int k = 0; k < 8; k++) {
            s += stats[k * 64 + b * 16 + tx];
            q += stats[k * 64 + 32 + b * 16 + tx];
        }
        float mean = s * (1.0f / (4.0f * HW));
        float var  = q * (1.0f / (4.0f * HW)) - mean * mean;
        mg[tx] = mean; rg[tx] = rsqrtf(var + 1e-5f);
    }
    if (tx < 64) { gam[tx] = gamma[tx]; bet[tx] = beta[tx]; }
    __syncthreads();

    if (tx < 198) {
        int hr = tx / 66, hc = tx - hr * 66;
        int ii = i + hr - 1, jj = j0 + hc - 1;
        float msum = 0.f, mmax = 0.f;
        if (ii >= 0 && ii < H && jj >= 0 && jj < W) {
            int pixg = ii * W + jj;
            for (int c = 0; c < 64; c++) {
                float v = dc[((size_t)b * 64 + c) * HW + pixg];
                int g = c >> 2;
                v = fmaxf((v - mg[g]) * rg[g] * gam[c] + bet[c], 0.f);
                msum += v;
                mmax = fmaxf(mmax, v);
            }
            cm_l[hr][hc] = msum * (1.0f / 64.0f);
            cx_l[hr][hc] = mmax;
        } else {
            cm_l[hr][hc] = 0.f;
            cx_l[hr][hc] = 0.f;
        }
    }
    {
        int tr = tx >> 6, tc = tx & 63;
        #pragma unroll
        for (int r = 0; r < 16; r++) {
            int c = r * 4 + tr;
            float v = dc[((size_t)b * 64 + c) * HW + p0 + tc];
            tile[c][tc] = fmaxf((v - mg[c >> 2]) * rg[c >> 2] * gam[c] + bet[c], 0.f);
        }
    }
    __syncthreads();

    if (tx < 64) {
        int p = tx;
        float sa = ba[0], sb = bb[0];
        #pragma unroll
        for (int di = 0; di < 3; di++) {
            #pragma unroll
            for (int dj = 0; dj < 3; dj++) {
                sa = fmaf(cm_l[di][p + dj], wa[di * 3 + dj], sa);
                sb = fmaf(cx_l[di][p + dj], wb[di * 3 + dj], sb);
            }
        }
        avs[p] = sigmoidf_(sa);
        mvs[p] = sigmoidf_(sb);
    }
    __syncthreads();

    {
        int tr = tx >> 6, tc = tx & 63;
        #pragma unroll
        for (int r = 0; r < 16; r++) {
            int p = r * 4 + tr;
            float v = tile[tc][p];
            unsigned short* cr = catt + ((size_t)b * HW + p0 + p) * 128;
            cr[tc]      = f2bf(avs[p] * v);
            cr[64 + tc] = f2bf(mvs[p] * v);
        }
    }
}

// ---------------------------------------------------------------------------
// Final GN + relu -> d_out (finalize from 8 per-XCD sums via LDS)
// ---------------------------------------------------------------------------
__global__ __launch_bounds__(256) void gn_final(
    const float* __restrict__ dc, const float* __restrict__ stats,
    const float* __restrict__ gamma, const float* __restrict__ beta,
    float* __restrict__ out)
{
    __shared__ float mg[32], rg[32];
    if (threadIdx.x < 32) {
        int bb = threadIdx.x >> 4, g = threadIdx.x & 15;
        float s = 0.f, q = 0.f;
        #pragma unroll
        for (int k = 0; k < 8; k++) {
            s += stats[k * 64 + bb * 16 + g];
            q += stats[k * 64 + 32 + bb * 16 + g];
        }
        float mean = s * (1.0f / (4.0f * HW));
        float var  = q * (1.0f / (4.0f * HW)) - mean * mean;
        mg[threadIdx.x] = mean;
        rg[threadIdx.x] = rsqrtf(var + 1e-5f);
    }
    __syncthreads();
    int t = blockIdx.x * 256 + threadIdx.x;
    if (t >= BATCH * 64 * HW) return;
    int c = (t >> 14) & 63;
    int b = t >> 20;
    int g = c >> 2;
    float v = (dc[t] - mg[b * 16 + g]) * rg[b * 16 + g] * gamma[c] + beta[c];
    out[t] = fmaxf(v, 0.f);
}

// ---------------------------------------------------------------------------
extern "C" void kernel_launch(void* const* d_in, const int* in_sizes, int n_in,
                              void* d_out, int out_size, void* d_ws, size_t ws_size,
                              hipStream_t stream) {
    (void)in_sizes; (void)n_in; (void)out_size; (void)ws_size;
    const float* x   = (const float*)d_in[0];
    const float* wp1 = (const float*)d_in[1];
    const float* bp1 = (const float*)d_in[2];
    const float* wm1 = (const float*)d_in[3];
    const float* bm1 = (const float*)d_in[4];
    const float* wc1 = (const float*)d_in[5];
    const float* g1  = (const float*)d_in[6];
    const float* be1 = (const float*)d_in[7];
    const float* wa  = (const float*)d_in[8];
    const float* ba  = (const float*)d_in[9];
    const float* wb  = (const float*)d_in[10];
    const float* bb  = (const float*)d_in[11];
    const float* wp2 = (const float*)d_in[12];
    const float* bp2 = (const float*)d_in[13];
    const float* wm2 = (const float*)d_in[14];
    const float* bm2 = (const float*)d_in[15];
    const float* wc2 = (const float*)d_in[16];
    const float* g2  = (const float*)d_in[17];
    const float* be2 = (const float*)d_in[18];
    float* out = (float*)d_out;

    // ---- workspace layout ----
    float* ws   = (float*)d_ws;
    float* dcb  = ws;                              // 2097152 f
    unsigned short* catt = (unsigned short*)(dcb + 2 * 64 * HW); // 2*HW*128 u16
    float* st1  = (float*)(catt + (size_t)2 * 128 * HW);         // 8*64 f
    float* st2  = st1 + 512;                                     // 8*64 f
    unsigned short* wtp1 = (unsigned short*)(st2 + 512);         // 64*576
    unsigned short* wtp2 = wtp1 + 64 * 576;                      // 64*1152
    unsigned short* wop1 = wtp2 + 64 * 1152;                     // 32*576
    unsigned short* wop2 = wop1 + 32 * 576;                      // 32*1152
    // x transposed [B][HW][64] bf16 in d_out scratch (rewritten by gn_final)
    unsigned short* xt1 = (unsigned short*)out;

    const int NDEF  = BATCH * HW / 64;               // 512
    const int NPREP = 512 + (64 * 576 + 64 * 1152 + 32 * 576 + 32 * 1152 + 255) / 256;

    prep_all<<<NPREP, 256, 0, stream>>>(x, wc1, wc2, wp1, wm1, wp2, wm2,
                                        xt1, wtp1, wtp2, wop1, wop2, st1, st2);

    // ---- stage 1 ----
    dsa_fused<64><<<NDEF, 256, 0, stream>>>(xt1, wop1, wtp1, bp1, bm1, dcb, st1);
    attn_cat_t<<<512, 256, 0, stream>>>(dcb, st1, g1, be1,
                                        wa, ba, wb, bb, catt);

    // ---- stage 2 ----
    dsa_fused<128><<<NDEF, 256, 0, stream>>>(catt, wop2, wtp2, bp2, bm2, dcb, st2);
    gn_final<<<(BATCH * 64 * HW + 255) / 256, 256, 0, stream>>>(dcb, st2, g2, be2, out);
}

// Round 20
// 93.299 us; speedup vs baseline: 1.7291x; 1.7291x over previous
//
#include <hip/hip_runtime.h>
#include <hip/hip_bf16.h>
#include <math.h>

#define H 128
#define W 128
#define HW (H*W)
#define BATCH 2

typedef __attribute__((ext_vector_type(8))) short          bf16x8;
typedef __attribute__((ext_vector_type(4))) float          f32x4;
typedef __attribute__((ext_vector_type(8))) unsigned short u16x8;

__device__ __forceinline__ float sigmoidf_(float x){ return 1.0f/(1.0f + expf(-x)); }

__device__ __forceinline__ unsigned short f2bf(float f) {
    __hip_bfloat16 h = __float2bfloat16(f);          // RTNE
    return __builtin_bit_cast(unsigned short, h);
}
__device__ __forceinline__ float bf2f(unsigned short b) {
    return __uint_as_float(((unsigned)b) << 16);
}
__device__ __forceinline__ float bflo(unsigned u){ return __uint_as_float(u << 16); }
__device__ __forceinline__ float bfhi(unsigned u){ return __uint_as_float(u & 0xFFFF0000u); }

// ---------------------------------------------------------------------------
// prep_all: blocks 0..31 zero the 64-copy GN-stat accumulators (2 x 4096 f);
// blocks 0..511 transpose x [B][64][HW] f32 -> xt [B][HW][64] bf16;
// blocks 512+ weight layouts.
// ---------------------------------------------------------------------------
__global__ __launch_bounds__(256) void prep_all(
    const float* __restrict__ x,
    const float* __restrict__ wc1, const float* __restrict__ wc2,
    const float* __restrict__ wp1, const float* __restrict__ wm1,
    const float* __restrict__ wp2, const float* __restrict__ wm2,
    unsigned short* __restrict__ xt,
    unsigned short* __restrict__ wtp1, unsigned short* __restrict__ wtp2,
    unsigned short* __restrict__ wop1, unsigned short* __restrict__ wop2,
    float* __restrict__ stats1, float* __restrict__ stats2)
{
    __shared__ float tile[64][65];
    if (blockIdx.x < 512) {
        if (blockIdx.x < 32) {
            int fidx = blockIdx.x * 256 + threadIdx.x;
            if (fidx < 4096) stats1[fidx] = 0.f;
            else             stats2[fidx - 4096] = 0.f;
        }
        int blk = blockIdx.x;
        int b  = blk >> 8;
        int p0 = (blk & 255) * 64;
        int tr = threadIdx.x >> 6;
        int tc = threadIdx.x & 63;
        #pragma unroll
        for (int r = 0; r < 16; r++) {
            int c = r * 4 + tr;
            tile[c][tc] = x[((size_t)b * 64 + c) * HW + p0 + tc];
        }
        __syncthreads();
        #pragma unroll
        for (int r = 0; r < 16; r++) {
            int p = r * 4 + tr;
            xt[((size_t)b * HW + p0 + p) * 64 + tc] = f2bf(tile[tc][p]);
        }
        return;
    }
    const int s1 = 64 * 9 * 64, s2 = 64 * 9 * 128;
    const int s3 = 32 * 9 * 64, s4 = 32 * 9 * 128;
    int t = (blockIdx.x - 512) * 256 + threadIdx.x;
    if (t < s1) {
        int oc = t / (9 * 64); int r = t - oc * (9 * 64);
        int n = r / 64, c = r - n * 64;
        wtp1[t] = f2bf(wc1[((size_t)oc * 64 + c) * 9 + n]);
        return;
    }
    t -= s1;
    if (t < s2) {
        int oc = t / (9 * 128); int r = t - oc * (9 * 128);
        int n = r / 128, c = r - n * 128;
        wtp2[t] = f2bf(wc2[((size_t)oc * 128 + c) * 9 + n]);
        return;
    }
    t -= s2;
    if (t < s3) {
        int oc = t / (9 * 64); int r = t - oc * (9 * 64);
        int n = r / 64, c = r - n * 64;
        float v = 0.f;
        if (oc < 18)      v = wp1[((size_t)oc * 64 + c) * 9 + n];
        else if (oc < 27) v = wm1[((size_t)(oc - 18) * 64 + c) * 9 + n];
        wop1[t] = f2bf(v);
        return;
    }
    t -= s3;
    if (t < s4) {
        int oc = t / (9 * 128); int r = t - oc * (9 * 128);
        int n = r / 128, c = r - n * 128;
        float v = 0.f;
        if (oc < 18)      v = wp2[((size_t)oc * 128 + c) * 9 + n];
        else if (oc < 27) v = wm2[((size_t)(oc - 18) * 128 + c) * 9 + n];
        wop2[t] = f2bf(v);
    }
}

// ---------------------------------------------------------------------------
// Fused DSA stage, 32-pixel tiles, 256 threads, 1024 blocks (R15/R17
// structure). GN-stat atomics go to one of 64 copies (bid & 63) -> XCD-local
// AND 8x less per-line contention than R17.
// ---------------------------------------------------------------------------
template<int CIN>
__global__ __launch_bounds__(256, 4) void dsa_fused(
    const unsigned short* __restrict__ xt,  // [B][HW][CIN] bf16
    const unsigned short* __restrict__ wop, // [32][9*CIN] bf16 tap-major
    const unsigned short* __restrict__ wtp, // [64][9*CIN] bf16 tap-major
    const float* __restrict__ bp,           // [18]
    const float* __restrict__ bm,           // [9]
    float* __restrict__ out,                // [B][64][HW]
    float* __restrict__ stats)              // [64][64] sums
{
    constexpr int HPC  = CIN / 64;
    constexpr int NCH  = 9 * HPC;
    constexpr int SROW = 68;
    __shared__ __align__(16) unsigned short sbuf[2][32][SROW];
    __shared__ __align__(16) unsigned short wbuf[2][64][SROW];
    __shared__ __align__(16) unsigned short meta[9][32][8];
    __shared__ float offlds[27][36];
    __shared__ float wsp[4][8][2];

    int tid  = threadIdx.x;
    int bid  = blockIdx.x;                  // 1024 blocks, XCD-bijective swizzle
    int wgid = (bid & 7) * 128 + (bid >> 3);
    int pix0 = wgid * 32;
    int b    = pix0 >> 14;
    int base = pix0 & (HW - 1);
    int i    = base >> 7;
    int j0   = base & 127;

    const unsigned short* xtb = xt + (size_t)b * HW * CIN;
    const u16x8 zero8 = {0,0,0,0,0,0,0,0};

    int lane = tid & 63, wv = tid >> 6;     // 4 waves
    int lr = lane & 15, lg = lane >> 4;
    int sp = tid >> 3, scl = tid & 7;       // sampling task: pixel, segment

    // ================= phase 1: offset/mask conv =================
    {
        u16x8 sv, wvr;
        auto sload = [&](int cc) {
            int n = cc / HPC, h = cc - n * HPC;
            int di = n / 3 - 1, dj = n - (n / 3) * 3 - 1;
            int ii = i + di;
            int jj = j0 + sp + dj;
            bool ok = (ii >= 0 && ii < H) && (jj >= 0 && jj < W);
            sv = ok ? *reinterpret_cast<const u16x8*>(
                          xtb + (size_t)(ii * W + jj) * CIN + h * 64 + scl * 8)
                    : zero8;
        };
        auto scommit = [&](int bi) {
            *reinterpret_cast<u16x8*>(&sbuf[bi][sp][scl * 8]) = sv;
        };
        auto wload = [&](int cc) {          // 32 rows x 8 segs = 256 slots
            int n = cc / HPC, h = cc - n * HPC;
            wvr = *reinterpret_cast<const u16x8*>(
                wop + (size_t)sp * (9 * CIN) + n * CIN + h * 64 + scl * 8);
        };
        auto wcommit = [&](int bi) {
            *reinterpret_cast<u16x8*>(&wbuf[bi][sp][scl * 8]) = wvr;
        };

        sload(0); wload(0);
        scommit(0); wcommit(0);
        __syncthreads();

        int mt = wv & 1, nt = wv >> 1;      // oc-half, pix-half
        int srow = nt * 16 + lr;
        int wrow = mt * 16 + lr;
        f32x4 acc = {0.f, 0.f, 0.f, 0.f};

        for (int cc = 0; cc < NCH; cc++) {
            int cur = cc & 1;
            if (cc + 1 < NCH) { sload(cc + 1); wload(cc + 1); }  // issue early
            #pragma unroll
            for (int ks = 0; ks < 2; ks++) {
                bf16x8 bfr = *reinterpret_cast<const bf16x8*>(&sbuf[cur][srow][ks * 32 + lg * 8]);
                bf16x8 a   = *reinterpret_cast<const bf16x8*>(&wbuf[cur][wrow][ks * 32 + lg * 8]);
                acc = __builtin_amdgcn_mfma_f32_16x16x32_bf16(a, bfr, acc, 0, 0, 0);
            }
            if (cc + 1 < NCH) { scommit(cur ^ 1); wcommit(cur ^ 1); }
            __syncthreads();
        }

        int plocal = nt * 16 + lr;
        #pragma unroll
        for (int r = 0; r < 4; r++) {
            int oc = mt * 16 + lg * 4 + r;
            if (oc < 27) {
                float v = acc[r];
                v = (oc < 18) ? (v + bp[oc]) : sigmoidf_(v + bm[oc - 18]);
                offlds[oc][plocal] = v;
            }
        }
    }
    __syncthreads();

    // ================= phase 2: bilinear meta (288 tasks) =================
    for (int task = tid; task < 288; task += 256) {
        int p = task & 31, n = task >> 5;
        int j = j0 + p;
        float px = offlds[n][p]      + (float)(n / 3 - 1) + (float)(i + 1);
        float py = offlds[9 + n][p]  + (float)(n % 3 - 1) + (float)(j + 1);
        float mk = offlds[18 + n][p];
        float fx = floorf(px), fy = floorf(py);
        const float lim = 129.0f;
        int qltx = (int)fminf(fmaxf(fx, 0.f), lim);
        int qlty = (int)fminf(fmaxf(fy, 0.f), lim);
        int qrbx = (int)fminf(fmaxf(fx + 1.f, 0.f), lim);
        int qrby = (int)fminf(fmaxf(fy + 1.f, 0.f), lim);
        float pxc = fminf(fmaxf(px, 0.f), lim);
        float pyc = fminf(fmaxf(py, 0.f), lim);
        float gxl = 1.f + ((float)qltx - pxc);
        float gxr = 1.f - ((float)qrbx - pxc);
        float gyl = 1.f + ((float)qlty - pyc);
        float gyr = 1.f - ((float)qrby - pyc);
        int   xs[4] = {qltx, qrbx, qltx, qrbx};
        int   ys[4] = {qlty, qrby, qrby, qlty};
        float gs[4] = {gxl * gyl, gxr * gyr, gxl * gyr, gxr * gyl};
        u16x8 m;
        #pragma unroll
        for (int q = 0; q < 4; q++) {
            int qx = xs[q], qy = ys[q];
            bool valid = (qx >= 1 && qx <= H && qy >= 1 && qy <= W);
            m[q]     = valid ? (unsigned short)((qx - 1) * W + (qy - 1)) : (unsigned short)0;
            m[4 + q] = f2bf(valid ? gs[q] * mk : 0.f);
        }
        *reinterpret_cast<u16x8*>(&meta[n][p][0]) = m;
    }
    __syncthreads();

    // ================= phase 3: deformable conv =================
    {
        u16x8 gv0, gv1, gv2, gv3, gm;
        u16x8 pw0, pw1;
        auto gload = [&](int cc) {
            int n = cc / HPC, h = cc - n * HPC;
            gm = *reinterpret_cast<const u16x8*>(&meta[n][sp][0]);
            const unsigned short* cb = xtb + h * 64 + scl * 8;
            gv0 = *reinterpret_cast<const u16x8*>(cb + (size_t)gm[0] * CIN);
            gv1 = *reinterpret_cast<const u16x8*>(cb + (size_t)gm[1] * CIN);
            gv2 = *reinterpret_cast<const u16x8*>(cb + (size_t)gm[2] * CIN);
            gv3 = *reinterpret_cast<const u16x8*>(cb + (size_t)gm[3] * CIN);
        };
        auto gcommit = [&](int bi) {
            float vac[8];
            #pragma unroll
            for (int e = 0; e < 8; e++) vac[e] = 0.f;
            const u16x8* gvs[4] = {&gv0, &gv1, &gv2, &gv3};
            #pragma unroll
            for (int q = 0; q < 4; q++) {
                float wq = bf2f(gm[4 + q]);
                const unsigned* vd = reinterpret_cast<const unsigned*>(gvs[q]);
                #pragma unroll
                for (int d = 0; d < 4; d++) {
                    vac[2 * d]     = fmaf(bflo(vd[d]), wq, vac[2 * d]);
                    vac[2 * d + 1] = fmaf(bfhi(vd[d]), wq, vac[2 * d + 1]);
                }
            }
            u16x8 o;
            #pragma unroll
            for (int e = 0; e < 8; e++) o[e] = f2bf(vac[e]);
            *reinterpret_cast<u16x8*>(&sbuf[bi][sp][scl * 8]) = o;
        };
        auto wload = [&](int cc) {          // 64 rows x 8 segs = 512 slots
            int n = cc / HPC, h = cc - n * HPC;
            const unsigned short* wb = wtp + n * CIN + h * 64;
            pw0 = *reinterpret_cast<const u16x8*>(wb + (size_t)(tid >> 3) * (9 * CIN) + (tid & 7) * 8);
            int idx = 256 + tid;
            pw1 = *reinterpret_cast<const u16x8*>(wb + (size_t)(idx >> 3) * (9 * CIN) + (idx & 7) * 8);
        };
        auto wcommit = [&](int bi) {
            *reinterpret_cast<u16x8*>(&wbuf[bi][tid >> 3][(tid & 7) * 8]) = pw0;
            int idx = 256 + tid;
            *reinterpret_cast<u16x8*>(&wbuf[bi][idx >> 3][(idx & 7) * 8]) = pw1;
        };

        gload(0); wload(0);
        gcommit(0); wcommit(0);
        __syncthreads();

        int ocq = wv & 1, pq = wv >> 1;     // oc-half, pix-half
        int srow = pq * 16 + lr;
        int wrow = ocq * 32 + lr;

        f32x4 acc0 = {0.f, 0.f, 0.f, 0.f};
        f32x4 acc1 = {0.f, 0.f, 0.f, 0.f};

        for (int cc = 0; cc < NCH; cc++) {
            int cur = cc & 1;
            if (cc + 1 < NCH) { gload(cc + 1); wload(cc + 1); }  // issue early
            #pragma unroll
            for (int ks = 0; ks < 2; ks++) {
                bf16x8 bfr = *reinterpret_cast<const bf16x8*>(&sbuf[cur][srow][ks * 32 + lg * 8]);
                bf16x8 a0  = *reinterpret_cast<const bf16x8*>(&wbuf[cur][wrow][ks * 32 + lg * 8]);
                bf16x8 a1  = *reinterpret_cast<const bf16x8*>(&wbuf[cur][wrow + 16][ks * 32 + lg * 8]);
                acc0 = __builtin_amdgcn_mfma_f32_16x16x32_bf16(a0, bfr, acc0, 0, 0, 0);
                acc1 = __builtin_amdgcn_mfma_f32_16x16x32_bf16(a1, bfr, acc1, 0, 0, 0);
            }
            if (cc + 1 < NCH) { gcommit(cur ^ 1); wcommit(cur ^ 1); }
            __syncthreads();
        }

        int pixo = base + pq * 16 + lr;
        float* ob0 = out + ((size_t)b * 64 + ocq * 32 + lg * 4) * HW + pixo;
        #pragma unroll
        for (int r = 0; r < 4; r++) ob0[(size_t)r * HW] = acc0[r];
        float* ob1 = out + ((size_t)b * 64 + ocq * 32 + 16 + lg * 4) * HW + pixo;
        #pragma unroll
        for (int r = 0; r < 4; r++) ob1[(size_t)r * HW] = acc1[r];

        // ---- GN-stat accumulation into this block's copy (bid & 63) ----
        float s0 = 0.f, q0 = 0.f, s1 = 0.f, q1 = 0.f;
        #pragma unroll
        for (int r = 0; r < 4; r++) {
            s0 += acc0[r]; q0 += acc0[r] * acc0[r];
            s1 += acc1[r]; q1 += acc1[r] * acc1[r];
        }
        #pragma unroll
        for (int d = 1; d < 16; d <<= 1) {
            s0 += __shfl_xor(s0, d); q0 += __shfl_xor(q0, d);
            s1 += __shfl_xor(s1, d); q1 += __shfl_xor(q1, d);
        }
        if (lr == 0) {
            wsp[wv][lg][0]     = s0; wsp[wv][lg][1]     = q0;
            wsp[wv][4 + lg][0] = s1; wsp[wv][4 + lg][1] = q1;
        }
        __syncthreads();
        if (tid < 16) {
            int g = tid, par = g >> 3, e = g & 7;
            float ss = wsp[par][e][0] + wsp[par + 2][e][0];
            float qq = wsp[par][e][1] + wsp[par + 2][e][1];
            float* sb = stats + (bid & 63) * 64;     // 64 copies
            atomicAdd(&sb[b * 16 + g], ss);
            atomicAdd(&sb[32 + b * 16 + g], qq);
        }
    }
}

// ---------------------------------------------------------------------------
// Fused: GN finalize (sum 64 copies) + halo channel-mean/max + 3x3 sigmoid
// conv + GN+relu + scale + concat + transpose -> bf16 catt
// ---------------------------------------------------------------------------
__global__ __launch_bounds__(256) void attn_cat_t(
    const float* __restrict__ dc, const float* __restrict__ stats,
    const float* __restrict__ gamma, const float* __restrict__ beta,
    const float* __restrict__ wa, const float* __restrict__ ba,
    const float* __restrict__ wb, const float* __restrict__ bb,
    unsigned short* __restrict__ catt)
{
    __shared__ float tile[64][65];
    __shared__ float cm_l[3][66], cx_l[3][66];
    __shared__ float avs[64], mvs[64];
    __shared__ float mg[16], rg[16], gam[64], bet[64];
    int blk = blockIdx.x;               // 512
    int b  = blk >> 8;
    int p0 = (blk & 255) * 64;
    int i  = p0 >> 7;
    int j0 = p0 & 127;
    int tx = threadIdx.x;

    if (tx < 16) {
        float s = 0.f, q = 0.f;
        for (int k = 0; k < 64; k++) {
            s += stats[k * 64 + b * 16 + tx];
            q += stats[k * 64 + 32 + b * 16 + tx];
        }
        float mean = s * (1.0f / (4.0f * HW));
        float var  = q * (1.0f / (4.0f * HW)) - mean * mean;
        mg[tx] = mean; rg[tx] = rsqrtf(var + 1e-5f);
    }
    if (tx < 64) { gam[tx] = gamma[tx]; bet[tx] = beta[tx]; }
    __syncthreads();

    if (tx < 198) {
        int hr = tx / 66, hc = tx - hr * 66;
        int ii = i + hr - 1, jj = j0 + hc - 1;
        float msum = 0.f, mmax = 0.f;
        if (ii >= 0 && ii < H && jj >= 0 && jj < W) {
            int pixg = ii * W + jj;
            for (int c = 0; c < 64; c++) {
                float v = dc[((size_t)b * 64 + c) * HW + pixg];
                int g = c >> 2;
                v = fmaxf((v - mg[g]) * rg[g] * gam[c] + bet[c], 0.f);
                msum += v;
                mmax = fmaxf(mmax, v);
            }
            cm_l[hr][hc] = msum * (1.0f / 64.0f);
            cx_l[hr][hc] = mmax;
        } else {
            cm_l[hr][hc] = 0.f;
            cx_l[hr][hc] = 0.f;
        }
    }
    {
        int tr = tx >> 6, tc = tx & 63;
        #pragma unroll
        for (int r = 0; r < 16; r++) {
            int c = r * 4 + tr;
            float v = dc[((size_t)b * 64 + c) * HW + p0 + tc];
            tile[c][tc] = fmaxf((v - mg[c >> 2]) * rg[c >> 2] * gam[c] + bet[c], 0.f);
        }
    }
    __syncthreads();

    if (tx < 64) {
        int p = tx;
        float sa = ba[0], sb = bb[0];
        #pragma unroll
        for (int di = 0; di < 3; di++) {
            #pragma unroll
            for (int dj = 0; dj < 3; dj++) {
                sa = fmaf(cm_l[di][p + dj], wa[di * 3 + dj], sa);
                sb = fmaf(cx_l[di][p + dj], wb[di * 3 + dj], sb);
            }
        }
        avs[p] = sigmoidf_(sa);
        mvs[p] = sigmoidf_(sb);
    }
    __syncthreads();

    {
        int tr = tx >> 6, tc = tx & 63;
        #pragma unroll
        for (int r = 0; r < 16; r++) {
            int p = r * 4 + tr;
            float v = tile[tc][p];
            unsigned short* cr = catt + ((size_t)b * HW + p0 + p) * 128;
            cr[tc]      = f2bf(avs[p] * v);
            cr[64 + tc] = f2bf(mvs[p] * v);
        }
    }
}

// ---------------------------------------------------------------------------
// Final GN + relu -> d_out (finalize from 64 copies via LDS)
// ---------------------------------------------------------------------------
__global__ __launch_bounds__(256) void gn_final(
    const float* __restrict__ dc, const float* __restrict__ stats,
    const float* __restrict__ gamma, const float* __restrict__ beta,
    float* __restrict__ out)
{
    __shared__ float mg[32], rg[32];
    if (threadIdx.x < 32) {
        int bb = threadIdx.x >> 4, g = threadIdx.x & 15;
        float s = 0.f, q = 0.f;
        for (int k = 0; k < 64; k++) {
            s += stats[k * 64 + bb * 16 + g];
            q += stats[k * 64 + 32 + bb * 16 + g];
        }
        float mean = s * (1.0f / (4.0f * HW));
        float var  = q * (1.0f / (4.0f * HW)) - mean * mean;
        mg[threadIdx.x] = mean;
        rg[threadIdx.x] = rsqrtf(var + 1e-5f);
    }
    __syncthreads();
    int t = blockIdx.x * 256 + threadIdx.x;
    if (t >= BATCH * 64 * HW) return;
    int c = (t >> 14) & 63;
    int b = t >> 20;
    int g = c >> 2;
    float v = (dc[t] - mg[b * 16 + g]) * rg[b * 16 + g] * gamma[c] + beta[c];
    out[t] = fmaxf(v, 0.f);
}

// ---------------------------------------------------------------------------
extern "C" void kernel_launch(void* const* d_in, const int* in_sizes, int n_in,
                              void* d_out, int out_size, void* d_ws, size_t ws_size,
                              hipStream_t stream) {
    (void)in_sizes; (void)n_in; (void)out_size; (void)ws_size;
    const float* x   = (const float*)d_in[0];
    const float* wp1 = (const float*)d_in[1];
    const float* bp1 = (const float*)d_in[2];
    const float* wm1 = (const float*)d_in[3];
    const float* bm1 = (const float*)d_in[4];
    const float* wc1 = (const float*)d_in[5];
    const float* g1  = (const float*)d_in[6];
    const float* be1 = (const float*)d_in[7];
    const float* wa  = (const float*)d_in[8];
    const float* ba  = (const float*)d_in[9];
    const float* wb  = (const float*)d_in[10];
    const float* bb  = (const float*)d_in[11];
    const float* wp2 = (const float*)d_in[12];
    const float* bp2 = (const float*)d_in[13];
    const float* wm2 = (const float*)d_in[14];
    const float* bm2 = (const float*)d_in[15];
    const float* wc2 = (const float*)d_in[16];
    const float* g2  = (const float*)d_in[17];
    const float* be2 = (const float*)d_in[18];
    float* out = (float*)d_out;

    // ---- workspace layout ----
    float* ws   = (float*)d_ws;
    float* dcb  = ws;                              // 2097152 f
    unsigned short* catt = (unsigned short*)(dcb + 2 * 64 * HW); // 2*HW*128 u16
    float* st1  = (float*)(catt + (size_t)2 * 128 * HW);         // 64*64 f
    float* st2  = st1 + 4096;                                    // 64*64 f
    unsigned short* wtp1 = (unsigned short*)(st2 + 4096);        // 64*576
    unsigned short* wtp2 = wtp1 + 64 * 576;                      // 64*1152
    unsigned short* wop1 = wtp2 + 64 * 1152;                     // 32*576
    unsigned short* wop2 = wop1 + 32 * 576;                      // 32*1152
    // x transposed [B][HW][64] bf16 in d_out scratch (rewritten by gn_final)
    unsigned short* xt1 = (unsigned short*)out;

    const int NDEF  = BATCH * HW / 32;               // 1024
    const int NPREP = 512 + (64 * 576 + 64 * 1152 + 32 * 576 + 32 * 1152 + 255) / 256;

    prep_all<<<NPREP, 256, 0, stream>>>(x, wc1, wc2, wp1, wm1, wp2, wm2,
                                        xt1, wtp1, wtp2, wop1, wop2, st1, st2);

    // ---- stage 1 ----
    dsa_fused<64><<<NDEF, 256, 0, stream>>>(xt1, wop1, wtp1, bp1, bm1, dcb, st1);
    attn_cat_t<<<512, 256, 0, stream>>>(dcb, st1, g1, be1,
                                        wa, ba, wb, bb, catt);

    // ---- stage 2 ----
    dsa_fused<128><<<NDEF, 256, 0, stream>>>(catt, wop2, wtp2, bp2, bm2, dcb, st2);
    gn_final<<<(BATCH * 64 * HW + 255) / 256, 256, 0, stream>>>(dcb, st2, g2, be2, out);
}

// Round 21
// 84.856 us; speedup vs baseline: 1.9011x; 1.0995x over previous
//
#include <hip/hip_runtime.h>
#include <hip/hip_bf16.h>
#include <math.h>

#define H 128
#define W 128
#define HW (H*W)
#define BATCH 2

typedef __attribute__((ext_vector_type(8))) short          bf16x8;
typedef __attribute__((ext_vector_type(4))) float          f32x4;
typedef __attribute__((ext_vector_type(8))) unsigned short u16x8;

__device__ __forceinline__ float sigmoidf_(float x){ return 1.0f/(1.0f + expf(-x)); }

__device__ __forceinline__ unsigned short f2bf(float f) {
    __hip_bfloat16 h = __float2bfloat16(f);          // RTNE
    return __builtin_bit_cast(unsigned short, h);
}
__device__ __forceinline__ float bf2f(unsigned short b) {
    return __uint_as_float(((unsigned)b) << 16);
}
__device__ __forceinline__ float bflo(unsigned u){ return __uint_as_float(u << 16); }
__device__ __forceinline__ float bfhi(unsigned u){ return __uint_as_float(u & 0xFFFF0000u); }

// ---------------------------------------------------------------------------
// prep_all: blocks 0/1 zero the per-XCD GN-stat accumulators (8 copies x 64);
// blocks 0..511 transpose x [B][64][HW] f32 -> xt [B][HW][64] bf16;
// blocks 512+ weight layouts.
// ---------------------------------------------------------------------------
__global__ __launch_bounds__(256) void prep_all(
    const float* __restrict__ x,
    const float* __restrict__ wc1, const float* __restrict__ wc2,
    const float* __restrict__ wp1, const float* __restrict__ wm1,
    const float* __restrict__ wp2, const float* __restrict__ wm2,
    unsigned short* __restrict__ xt,
    unsigned short* __restrict__ wtp1, unsigned short* __restrict__ wtp2,
    unsigned short* __restrict__ wop1, unsigned short* __restrict__ wop2,
    float* __restrict__ stats1, float* __restrict__ stats2)
{
    __shared__ float tile[64][65];
    if (blockIdx.x < 512) {
        if (blockIdx.x == 0) {
            stats1[threadIdx.x] = 0.f; stats1[threadIdx.x + 256] = 0.f;
        } else if (blockIdx.x == 1) {
            stats2[threadIdx.x] = 0.f; stats2[threadIdx.x + 256] = 0.f;
        }
        int blk = blockIdx.x;
        int b  = blk >> 8;
        int p0 = (blk & 255) * 64;
        int tr = threadIdx.x >> 6;
        int tc = threadIdx.x & 63;
        #pragma unroll
        for (int r = 0; r < 16; r++) {
            int c = r * 4 + tr;
            tile[c][tc] = x[((size_t)b * 64 + c) * HW + p0 + tc];
        }
        __syncthreads();
        #pragma unroll
        for (int r = 0; r < 16; r++) {
            int p = r * 4 + tr;
            xt[((size_t)b * HW + p0 + p) * 64 + tc] = f2bf(tile[tc][p]);
        }
        return;
    }
    const int s1 = 64 * 9 * 64, s2 = 64 * 9 * 128;
    const int s3 = 32 * 9 * 64, s4 = 32 * 9 * 128;
    int t = (blockIdx.x - 512) * 256 + threadIdx.x;
    if (t < s1) {
        int oc = t / (9 * 64); int r = t - oc * (9 * 64);
        int n = r / 64, c = r - n * 64;
        wtp1[t] = f2bf(wc1[((size_t)oc * 64 + c) * 9 + n]);
        return;
    }
    t -= s1;
    if (t < s2) {
        int oc = t / (9 * 128); int r = t - oc * (9 * 128);
        int n = r / 128, c = r - n * 128;
        wtp2[t] = f2bf(wc2[((size_t)oc * 128 + c) * 9 + n]);
        return;
    }
    t -= s2;
    if (t < s3) {
        int oc = t / (9 * 64); int r = t - oc * (9 * 64);
        int n = r / 64, c = r - n * 64;
        float v = 0.f;
        if (oc < 18)      v = wp1[((size_t)oc * 64 + c) * 9 + n];
        else if (oc < 27) v = wm1[((size_t)(oc - 18) * 64 + c) * 9 + n];
        wop1[t] = f2bf(v);
        return;
    }
    t -= s3;
    if (t < s4) {
        int oc = t / (9 * 128); int r = t - oc * (9 * 128);
        int n = r / 128, c = r - n * 128;
        float v = 0.f;
        if (oc < 18)      v = wp2[((size_t)oc * 128 + c) * 9 + n];
        else if (oc < 27) v = wm2[((size_t)(oc - 18) * 128 + c) * 9 + n];
        wop2[t] = f2bf(v);
    }
}

// ---------------------------------------------------------------------------
// Fused DSA stage, 32-pixel tiles, 256 threads, 1024 blocks (R15 structure).
// GN-stat atomics go to a PER-XCD copy (stats[(bid&7)*64 + ...]) to kill
// cross-XCD cache-line ping-pong.
// ---------------------------------------------------------------------------
template<int CIN>
__global__ __launch_bounds__(256, 4) void dsa_fused(
    const unsigned short* __restrict__ xt,  // [B][HW][CIN] bf16
    const unsigned short* __restrict__ wop, // [32][9*CIN] bf16 tap-major
    const unsigned short* __restrict__ wtp, // [64][9*CIN] bf16 tap-major
    const float* __restrict__ bp,           // [18]
    const float* __restrict__ bm,           // [9]
    float* __restrict__ out,                // [B][64][HW]
    float* __restrict__ stats)              // [8][64] per-XCD sums
{
    constexpr int HPC  = CIN / 64;
    constexpr int NCH  = 9 * HPC;
    constexpr int SROW = 68;
    __shared__ __align__(16) unsigned short sbuf[2][32][SROW];
    __shared__ __align__(16) unsigned short wbuf[2][64][SROW];
    __shared__ __align__(16) unsigned short meta[9][32][8];
    __shared__ float offlds[27][36];
    __shared__ float wsp[4][8][2];

    int tid  = threadIdx.x;
    int bid  = blockIdx.x;                  // 1024 blocks, XCD-bijective swizzle
    int wgid = (bid & 7) * 128 + (bid >> 3);
    int pix0 = wgid * 32;
    int b    = pix0 >> 14;
    int base = pix0 & (HW - 1);
    int i    = base >> 7;
    int j0   = base & 127;

    const unsigned short* xtb = xt + (size_t)b * HW * CIN;
    const u16x8 zero8 = {0,0,0,0,0,0,0,0};

    int lane = tid & 63, wv = tid >> 6;     // 4 waves
    int lr = lane & 15, lg = lane >> 4;
    int sp = tid >> 3, scl = tid & 7;       // sampling task: pixel, segment

    // ================= phase 1: offset/mask conv =================
    {
        u16x8 sv, wvr;
        auto sload = [&](int cc) {
            int n = cc / HPC, h = cc - n * HPC;
            int di = n / 3 - 1, dj = n - (n / 3) * 3 - 1;
            int ii = i + di;
            int jj = j0 + sp + dj;
            bool ok = (ii >= 0 && ii < H) && (jj >= 0 && jj < W);
            sv = ok ? *reinterpret_cast<const u16x8*>(
                          xtb + (size_t)(ii * W + jj) * CIN + h * 64 + scl * 8)
                    : zero8;
        };
        auto scommit = [&](int bi) {
            *reinterpret_cast<u16x8*>(&sbuf[bi][sp][scl * 8]) = sv;
        };
        auto wload = [&](int cc) {          // 32 rows x 8 segs = 256 slots
            int n = cc / HPC, h = cc - n * HPC;
            wvr = *reinterpret_cast<const u16x8*>(
                wop + (size_t)sp * (9 * CIN) + n * CIN + h * 64 + scl * 8);
        };
        auto wcommit = [&](int bi) {
            *reinterpret_cast<u16x8*>(&wbuf[bi][sp][scl * 8]) = wvr;
        };

        sload(0); wload(0);
        scommit(0); wcommit(0);
        __syncthreads();

        int mt = wv & 1, nt = wv >> 1;      // oc-half, pix-half
        int srow = nt * 16 + lr;
        int wrow = mt * 16 + lr;
        f32x4 acc = {0.f, 0.f, 0.f, 0.f};

        for (int cc = 0; cc < NCH; cc++) {
            int cur = cc & 1;
            if (cc + 1 < NCH) { sload(cc + 1); wload(cc + 1); }  // issue early
            #pragma unroll
            for (int ks = 0; ks < 2; ks++) {
                bf16x8 bfr = *reinterpret_cast<const bf16x8*>(&sbuf[cur][srow][ks * 32 + lg * 8]);
                bf16x8 a   = *reinterpret_cast<const bf16x8*>(&wbuf[cur][wrow][ks * 32 + lg * 8]);
                acc = __builtin_amdgcn_mfma_f32_16x16x32_bf16(a, bfr, acc, 0, 0, 0);
            }
            if (cc + 1 < NCH) { scommit(cur ^ 1); wcommit(cur ^ 1); }
            __syncthreads();
        }

        int plocal = nt * 16 + lr;
        #pragma unroll
        for (int r = 0; r < 4; r++) {
            int oc = mt * 16 + lg * 4 + r;
            if (oc < 27) {
                float v = acc[r];
                v = (oc < 18) ? (v + bp[oc]) : sigmoidf_(v + bm[oc - 18]);
                offlds[oc][plocal] = v;
            }
        }
    }
    __syncthreads();

    // ================= phase 2: bilinear meta (288 tasks) =================
    for (int task = tid; task < 288; task += 256) {
        int p = task & 31, n = task >> 5;
        int j = j0 + p;
        float px = offlds[n][p]      + (float)(n / 3 - 1) + (float)(i + 1);
        float py = offlds[9 + n][p]  + (float)(n % 3 - 1) + (float)(j + 1);
        float mk = offlds[18 + n][p];
        float fx = floorf(px), fy = floorf(py);
        const float lim = 129.0f;
        int qltx = (int)fminf(fmaxf(fx, 0.f), lim);
        int qlty = (int)fminf(fmaxf(fy, 0.f), lim);
        int qrbx = (int)fminf(fmaxf(fx + 1.f, 0.f), lim);
        int qrby = (int)fminf(fmaxf(fy + 1.f, 0.f), lim);
        float pxc = fminf(fmaxf(px, 0.f), lim);
        float pyc = fminf(fmaxf(py, 0.f), lim);
        float gxl = 1.f + ((float)qltx - pxc);
        float gxr = 1.f - ((float)qrbx - pxc);
        float gyl = 1.f + ((float)qlty - pyc);
        float gyr = 1.f - ((float)qrby - pyc);
        int   xs[4] = {qltx, qrbx, qltx, qrbx};
        int   ys[4] = {qlty, qrby, qrby, qlty};
        float gs[4] = {gxl * gyl, gxr * gyr, gxl * gyr, gxr * gyl};
        u16x8 m;
        #pragma unroll
        for (int q = 0; q < 4; q++) {
            int qx = xs[q], qy = ys[q];
            bool valid = (qx >= 1 && qx <= H && qy >= 1 && qy <= W);
            m[q]     = valid ? (unsigned short)((qx - 1) * W + (qy - 1)) : (unsigned short)0;
            m[4 + q] = f2bf(valid ? gs[q] * mk : 0.f);
        }
        *reinterpret_cast<u16x8*>(&meta[n][p][0]) = m;
    }
    __syncthreads();

    // ================= phase 3: deformable conv =================
    {
        u16x8 gv0, gv1, gv2, gv3, gm;
        u16x8 pw0, pw1;
        auto gload = [&](int cc) {
            int n = cc / HPC, h = cc - n * HPC;
            gm = *reinterpret_cast<const u16x8*>(&meta[n][sp][0]);
            const unsigned short* cb = xtb + h * 64 + scl * 8;
            gv0 = *reinterpret_cast<const u16x8*>(cb + (size_t)gm[0] * CIN);
            gv1 = *reinterpret_cast<const u16x8*>(cb + (size_t)gm[1] * CIN);
            gv2 = *reinterpret_cast<const u16x8*>(cb + (size_t)gm[2] * CIN);
            gv3 = *reinterpret_cast<const u16x8*>(cb + (size_t)gm[3] * CIN);
        };
        auto gcommit = [&](int bi) {
            float vac[8];
            #pragma unroll
            for (int e = 0; e < 8; e++) vac[e] = 0.f;
            const u16x8* gvs[4] = {&gv0, &gv1, &gv2, &gv3};
            #pragma unroll
            for (int q = 0; q < 4; q++) {
                float wq = bf2f(gm[4 + q]);
                const unsigned* vd = reinterpret_cast<const unsigned*>(gvs[q]);
                #pragma unroll
                for (int d = 0; d < 4; d++) {
                    vac[2 * d]     = fmaf(bflo(vd[d]), wq, vac[2 * d]);
                    vac[2 * d + 1] = fmaf(bfhi(vd[d]), wq, vac[2 * d + 1]);
                }
            }
            u16x8 o;
            #pragma unroll
            for (int e = 0; e < 8; e++) o[e] = f2bf(vac[e]);
            *reinterpret_cast<u16x8*>(&sbuf[bi][sp][scl * 8]) = o;
        };
        auto wload = [&](int cc) {          // 64 rows x 8 segs = 512 slots
            int n = cc / HPC, h = cc - n * HPC;
            const unsigned short* wb = wtp + n * CIN + h * 64;
            pw0 = *reinterpret_cast<const u16x8*>(wb + (size_t)(tid >> 3) * (9 * CIN) + (tid & 7) * 8);
            int idx = 256 + tid;
            pw1 = *reinterpret_cast<const u16x8*>(wb + (size_t)(idx >> 3) * (9 * CIN) + (idx & 7) * 8);
        };
        auto wcommit = [&](int bi) {
            *reinterpret_cast<u16x8*>(&wbuf[bi][tid >> 3][(tid & 7) * 8]) = pw0;
            int idx = 256 + tid;
            *reinterpret_cast<u16x8*>(&wbuf[bi][idx >> 3][(idx & 7) * 8]) = pw1;
        };

        gload(0); wload(0);
        gcommit(0); wcommit(0);
        __syncthreads();

        int ocq = wv & 1, pq = wv >> 1;     // oc-half, pix-half
        int srow = pq * 16 + lr;
        int wrow = ocq * 32 + lr;

        f32x4 acc0 = {0.f, 0.f, 0.f, 0.f};
        f32x4 acc1 = {0.f, 0.f, 0.f, 0.f};

        for (int cc = 0; cc < NCH; cc++) {
            int cur = cc & 1;
            if (cc + 1 < NCH) { gload(cc + 1); wload(cc + 1); }  // issue early
            #pragma unroll
            for (int ks = 0; ks < 2; ks++) {
                bf16x8 bfr = *reinterpret_cast<const bf16x8*>(&sbuf[cur][srow][ks * 32 + lg * 8]);
                bf16x8 a0  = *reinterpret_cast<const bf16x8*>(&wbuf[cur][wrow][ks * 32 + lg * 8]);
                bf16x8 a1  = *reinterpret_cast<const bf16x8*>(&wbuf[cur][wrow + 16][ks * 32 + lg * 8]);
                acc0 = __builtin_amdgcn_mfma_f32_16x16x32_bf16(a0, bfr, acc0, 0, 0, 0);
                acc1 = __builtin_amdgcn_mfma_f32_16x16x32_bf16(a1, bfr, acc1, 0, 0, 0);
            }
            if (cc + 1 < NCH) { gcommit(cur ^ 1); wcommit(cur ^ 1); }
            __syncthreads();
        }

        int pixo = base + pq * 16 + lr;
        float* ob0 = out + ((size_t)b * 64 + ocq * 32 + lg * 4) * HW + pixo;
        #pragma unroll
        for (int r = 0; r < 4; r++) ob0[(size_t)r * HW] = acc0[r];
        float* ob1 = out + ((size_t)b * 64 + ocq * 32 + 16 + lg * 4) * HW + pixo;
        #pragma unroll
        for (int r = 0; r < 4; r++) ob1[(size_t)r * HW] = acc1[r];

        // ---- GN-stat accumulation into this XCD's copy ----
        float s0 = 0.f, q0 = 0.f, s1 = 0.f, q1 = 0.f;
        #pragma unroll
        for (int r = 0; r < 4; r++) {
            s0 += acc0[r]; q0 += acc0[r] * acc0[r];
            s1 += acc1[r]; q1 += acc1[r] * acc1[r];
        }
        #pragma unroll
        for (int d = 1; d < 16; d <<= 1) {
            s0 += __shfl_xor(s0, d); q0 += __shfl_xor(q0, d);
            s1 += __shfl_xor(s1, d); q1 += __shfl_xor(q1, d);
        }
        if (lr == 0) {
            wsp[wv][lg][0]     = s0; wsp[wv][lg][1]     = q0;
            wsp[wv][4 + lg][0] = s1; wsp[wv][4 + lg][1] = q1;
        }
        __syncthreads();
        if (tid < 16) {
            int g = tid, par = g >> 3, e = g & 7;
            float ss = wsp[par][e][0] + wsp[par + 2][e][0];
            float qq = wsp[par][e][1] + wsp[par + 2][e][1];
            float* sb = stats + (bid & 7) * 64;     // per-XCD copy
            atomicAdd(&sb[b * 16 + g], ss);
            atomicAdd(&sb[32 + b * 16 + g], qq);
        }
    }
}

// ---------------------------------------------------------------------------
// Fused: GN finalize (sum 8 per-XCD copies) + halo channel-mean/max +
// 3x3 sigmoid conv + GN+relu + scale + concat + transpose -> bf16 catt
// ---------------------------------------------------------------------------
__global__ __launch_bounds__(256) void attn_cat_t(
    const float* __restrict__ dc, const float* __restrict__ stats,
    const float* __restrict__ gamma, const float* __restrict__ beta,
    const float* __restrict__ wa, const float* __restrict__ ba,
    const float* __restrict__ wb, const float* __restrict__ bb,
    unsigned short* __restrict__ catt)
{
    __shared__ float tile[64][65];
    __shared__ float cm_l[3][66], cx_l[3][66];
    __shared__ float avs[64], mvs[64];
    __shared__ float mg[16], rg[16], gam[64], bet[64];
    int blk = blockIdx.x;               // 512
    int b  = blk >> 8;
    int p0 = (blk & 255) * 64;
    int i  = p0 >> 7;
    int j0 = p0 & 127;
    int tx = threadIdx.x;

    if (tx < 16) {
        float s = 0.f, q = 0.f;
        #pragma unroll
        for (int k = 0; k < 8; k++) {
            s += stats[k * 64 + b * 16 + tx];
            q += stats[k * 64 + 32 + b * 16 + tx];
        }
        float mean = s * (1.0f / (4.0f * HW));
        float var  = q * (1.0f / (4.0f * HW)) - mean * mean;
        mg[tx] = mean; rg[tx] = rsqrtf(var + 1e-5f);
    }
    if (tx < 64) { gam[tx] = gamma[tx]; bet[tx] = beta[tx]; }
    __syncthreads();

    if (tx < 198) {
        int hr = tx / 66, hc = tx - hr * 66;
        int ii = i + hr - 1, jj = j0 + hc - 1;
        float msum = 0.f, mmax = 0.f;
        if (ii >= 0 && ii < H && jj >= 0 && jj < W) {
            int pixg = ii * W + jj;
            for (int c = 0; c < 64; c++) {
                float v = dc[((size_t)b * 64 + c) * HW + pixg];
                int g = c >> 2;
                v = fmaxf((v - mg[g]) * rg[g] * gam[c] + bet[c], 0.f);
                msum += v;
                mmax = fmaxf(mmax, v);
            }
            cm_l[hr][hc] = msum * (1.0f / 64.0f);
            cx_l[hr][hc] = mmax;
        } else {
            cm_l[hr][hc] = 0.f;
            cx_l[hr][hc] = 0.f;
        }
    }
    {
        int tr = tx >> 6, tc = tx & 63;
        #pragma unroll
        for (int r = 0; r < 16; r++) {
            int c = r * 4 + tr;
            float v = dc[((size_t)b * 64 + c) * HW + p0 + tc];
            tile[c][tc] = fmaxf((v - mg[c >> 2]) * rg[c >> 2] * gam[c] + bet[c], 0.f);
        }
    }
    __syncthreads();

    if (tx < 64) {
        int p = tx;
        float sa = ba[0], sb = bb[0];
        #pragma unroll
        for (int di = 0; di < 3; di++) {
            #pragma unroll
            for (int dj = 0; dj < 3; dj++) {
                sa = fmaf(cm_l[di][p + dj], wa[di * 3 + dj], sa);
                sb = fmaf(cx_l[di][p + dj], wb[di * 3 + dj], sb);
            }
        }
        avs[p] = sigmoidf_(sa);
        mvs[p] = sigmoidf_(sb);
    }
    __syncthreads();

    {
        int tr = tx >> 6, tc = tx & 63;
        #pragma unroll
        for (int r = 0; r < 16; r++) {
            int p = r * 4 + tr;
            float v = tile[tc][p];
            unsigned short* cr = catt + ((size_t)b * HW + p0 + p) * 128;
            cr[tc]      = f2bf(avs[p] * v);
            cr[64 + tc] = f2bf(mvs[p] * v);
        }
    }
}

// ---------------------------------------------------------------------------
// Final GN + relu -> d_out (finalize from 8 per-XCD sums via LDS)
// ---------------------------------------------------------------------------
__global__ __launch_bounds__(256) void gn_final(
    const float* __restrict__ dc, const float* __restrict__ stats,
    const float* __restrict__ gamma, const float* __restrict__ beta,
    float* __restrict__ out)
{
    __shared__ float mg[32], rg[32];
    if (threadIdx.x < 32) {
        int bb = threadIdx.x >> 4, g = threadIdx.x & 15;
        float s = 0.f, q = 0.f;
        #pragma unroll
        for (int k = 0; k < 8; k++) {
            s += stats[k * 64 + bb * 16 + g];
            q += stats[k * 64 + 32 + bb * 16 + g];
        }
        float mean = s * (1.0f / (4.0f * HW));
        float var  = q * (1.0f / (4.0f * HW)) - mean * mean;
        mg[threadIdx.x] = mean;
        rg[threadIdx.x] = rsqrtf(var + 1e-5f);
    }
    __syncthreads();
    int t = blockIdx.x * 256 + threadIdx.x;
    if (t >= BATCH * 64 * HW) return;
    int c = (t >> 14) & 63;
    int b = t >> 20;
    int g = c >> 2;
    float v = (dc[t] - mg[b * 16 + g]) * rg[b * 16 + g] * gamma[c] + beta[c];
    out[t] = fmaxf(v, 0.f);
}

// ---------------------------------------------------------------------------
extern "C" void kernel_launch(void* const* d_in, const int* in_sizes, int n_in,
                              void* d_out, int out_size, void* d_ws, size_t ws_size,
                              hipStream_t stream) {
    (void)in_sizes; (void)n_in; (void)out_size; (void)ws_size;
    const float* x   = (const float*)d_in[0];
    const float* wp1 = (const float*)d_in[1];
    const float* bp1 = (const float*)d_in[2];
    const float* wm1 = (const float*)d_in[3];
    const float* bm1 = (const float*)d_in[4];
    const float* wc1 = (const float*)d_in[5];
    const float* g1  = (const float*)d_in[6];
    const float* be1 = (const float*)d_in[7];
    const float* wa  = (const float*)d_in[8];
    const float* ba  = (const float*)d_in[9];
    const float* wb  = (const float*)d_in[10];
    const float* bb  = (const float*)d_in[11];
    const float* wp2 = (const float*)d_in[12];
    const float* bp2 = (const float*)d_in[13];
    const float* wm2 = (const float*)d_in[14];
    const float* bm2 = (const float*)d_in[15];
    const float* wc2 = (const float*)d_in[16];
    const float* g2  = (const float*)d_in[17];
    const float* be2 = (const float*)d_in[18];
    float* out = (float*)d_out;

    // ---- workspace layout ----
    float* ws   = (float*)d_ws;
    float* dcb  = ws;                              // 2097152 f
    unsigned short* catt = (unsigned short*)(dcb + 2 * 64 * HW); // 2*HW*128 u16
    float* st1  = (float*)(catt + (size_t)2 * 128 * HW);         // 8*64 f
    float* st2  = st1 + 512;                                     // 8*64 f
    unsigned short* wtp1 = (unsigned short*)(st2 + 512);         // 64*576
    unsigned short* wtp2 = wtp1 + 64 * 576;                      // 64*1152
    unsigned short* wop1 = wtp2 + 64 * 1152;                     // 32*576
    unsigned short* wop2 = wop1 + 32 * 576;                      // 32*1152
    // x transposed [B][HW][64] bf16 in d_out scratch (rewritten by gn_final)
    unsigned short* xt1 = (unsigned short*)out;

    const int NDEF  = BATCH * HW / 32;               // 1024
    const int NPREP = 512 + (64 * 576 + 64 * 1152 + 32 * 576 + 32 * 1152 + 255) / 256;

    prep_all<<<NPREP, 256, 0, stream>>>(x, wc1, wc2, wp1, wm1, wp2, wm2,
                                        xt1, wtp1, wtp2, wop1, wop2, st1, st2);

    // ---- stage 1 ----
    dsa_fused<64><<<NDEF, 256, 0, stream>>>(xt1, wop1, wtp1, bp1, bm1, dcb, st1);
    attn_cat_t<<<512, 256, 0, stream>>>(dcb, st1, g1, be1,
                                        wa, ba, wb, bb, catt);

    // ---- stage 2 ----
    dsa_fused<128><<<NDEF, 256, 0, stream>>>(catt, wop2, wtp2, bp2, bm2, dcb, st2);
    gn_final<<<(BATCH * 64 * HW + 255) / 256, 256, 0, stream>>>(dcb, st2, g2, be2, out);
}